// Round 6
// baseline (197.584 us; speedup 1.0000x reference)
//
#include <hip/hip_runtime.h>
#include <cstdint>
#include <cstddef>

typedef unsigned short u16;
typedef __attribute__((ext_vector_type(8))) short bf16x8;
typedef __attribute__((ext_vector_type(4))) float f32x4;

struct alignas(8) u16x4_t { u16 x, y, z, w; };

__device__ __forceinline__ u16 f2bf(float f) {
  uint32_t u = __builtin_bit_cast(uint32_t, f);
  u += 0x7FFFu + ((u >> 16) & 1u);          // round-to-nearest-even
  return (u16)(u >> 16);
}
__device__ __forceinline__ float bf2f(u16 h) {
  uint32_t u = ((uint32_t)h) << 16;
  return __builtin_bit_cast(float, u);
}

// async global->LDS, 16B per lane. LDS dest is wave-uniform base; HW adds lane*16.
// NOTE (R10 post-mortem): this is the ONLY sound async-staging primitive from
// HIP source. Direct global->VGPR via inline asm is unsound. Do not retry.
__device__ __forceinline__ void g2l16(const u16* g, u16* l) {
  __builtin_amdgcn_global_load_lds(
      (const __attribute__((address_space(1))) void*)g,
      (__attribute__((address_space(3))) void*)l, 16, 0, 0);
}

// gfx9 s_waitcnt imm: vmcnt[3:0]@0, expcnt@4 (3b), lgkmcnt@8 (4b), vmcnt[5:4]@14
#define S_WAITCNT_VM(N) \
  __builtin_amdgcn_s_waitcnt((((N) & 0xF)) | (0x7 << 4) | (0xF << 8) | ((((N) >> 4) & 3) << 14))
#define S_WAITCNT_LGKM0 __builtin_amdgcn_s_waitcnt(0xC07F)

// ---------------------------------------------------------------------------
// R15 software-pipelined bt-GEMM ring (4-wave, 256 threads). Benched-correct.
// Per step: vmcnt(T*(D-2)); barrier; read frags(tile k+1); MFMAs(tile k);
// barrier; issue(tile k+D). Counted vmcnt never drains to 0 in-loop.
// R14 post-mortem: never cap combined VGPR below acc size (spill -> 1 GB
// scratch traffic).
// ---------------------------------------------------------------------------
template <int DEPTH, int BM, int BN>
__device__ __forceinline__ void gemm_bt_pipe(
    const u16* __restrict__ A, const u16* __restrict__ Bt,
    int lda, int ldb, int kIters, int m0, int n0,
    u16* sh, f32x4 (&acc)[BM / 32][BN / 32]) {
  constexpr int MI = BM / 32;
  constexpr int NI = BN / 32;
  constexpr int T = (BM + BN) / 64;
  constexpr int SLOT = (BM + BN) * 32;
  const int tid = threadIdx.x;
  const int lane = tid & 63, wave = tid >> 6;
  const int wm = wave >> 1, wn = wave & 1, lr = lane & 15, quad = lane >> 4;

  const u16* gp[T];
#pragma unroll
  for (int t = 0; t < T; ++t) {
    const int c = t * 256 + wave * 64 + lane;
    if (c < BM * 4) {
      const int r = c >> 2;
      const int s = (c & 3) ^ ((r >> 1) & 3);
      gp[t] = A + (size_t)(m0 + r) * lda + s * 8;
    } else {
      const int cb = c - BM * 4;
      const int r = cb >> 2;
      const int s = (cb & 3) ^ ((r >> 1) & 3);
      gp[t] = Bt + (size_t)(n0 + r) * ldb + s * 8;
    }
  }
  const int wo = wave * 512;

  auto issue = [&](int slot, int kb) {
    u16* s = sh + slot * SLOT;
#pragma unroll
    for (int t = 0; t < T; ++t)
      g2l16(gp[t] + kb, s + t * 2048 + wo);
  };

#pragma unroll
  for (int p = 0; p < DEPTH; ++p)
    issue(p, (p < kIters ? p : kIters - 1) * 32);

  const int xq = (quad ^ ((lr >> 1) & 3)) * 8;
  const int arow = wm * (BM / 2) + lr;     // + mi*16
  const int brow = wn * (BN / 2) + lr;     // + ni*16

  bf16x8 af[MI], b0[NI], b1[NI];
  S_WAITCNT_VM(T * (DEPTH - 1));           // tile 0 landed (own)
  __builtin_amdgcn_s_barrier();            // tile 0 landed (all waves)
#pragma unroll
  for (int ni = 0; ni < NI; ++ni)
    b0[ni] = *(const bf16x8*)(sh + BM * 32 + ((brow + ni * 16) * 32 + xq));
#pragma unroll
  for (int mi = 0; mi < MI; ++mi)
    af[mi] = *(const bf16x8*)(sh + ((arow + mi * 16) * 32 + xq));

  auto step = [&](int kt, bf16x8 (&bc)[NI], bf16x8 (&bn)[NI]) {
    S_WAITCNT_VM(T * (DEPTH - 2));         // tiles <= kt+1 landed (own)
    __builtin_amdgcn_s_barrier();          // ... landed (all waves)
    const int nx = (kt + 1 < kIters) ? kt + 1 : kIters - 1;  // clamped tail
    u16* s1 = sh + (nx % DEPTH) * SLOT;
#pragma unroll
    for (int ni = 0; ni < NI; ++ni)
      bn[ni] = *(const bf16x8*)(s1 + BM * 32 + ((brow + ni * 16) * 32 + xq));
    __builtin_amdgcn_s_setprio(1);
#pragma unroll
    for (int mi = 0; mi < MI; ++mi) {
#pragma unroll
      for (int ni = 0; ni < NI; ++ni)
        acc[mi][ni] = __builtin_amdgcn_mfma_f32_16x16x32_bf16(af[mi], bc[ni], acc[mi][ni], 0, 0, 0);
      af[mi] = *(const bf16x8*)(s1 + ((arow + mi * 16) * 32 + xq));  // next tile
    }
    __builtin_amdgcn_s_setprio(0);
    __builtin_amdgcn_s_barrier();          // all tile-kt reads drained (by MFMAs)
    const int kn = kt + DEPTH;
    issue(kn % DEPTH, (kn < kIters ? kn : kIters - 1) * 32);
  };

  for (int kt = 0; kt + 2 <= kIters; kt += 2) {  // kIters even everywhere
    step(kt, b0, b1);
    step(kt + 1, b1, b0);
  }
}

// ---------------------------------------------------------------------------
// R15 8-wave variant (512 threads), wave grid 2(m) x 4(n), wave tile
// BM/2 x BN/4. Same software-pipelined ring as the 4-wave pipe.
// R17: reused for qkv at BM=128, BN=256 (acc[4][4] = 64 VGPR).
// ---------------------------------------------------------------------------
template <int DEPTH, int BM, int BN>
__device__ __forceinline__ void gemm_bt_pipe_w8(
    const u16* __restrict__ A, const u16* __restrict__ Bt,
    int lda, int ldb, int kIters, int m0, int n0,
    u16* sh, f32x4 (&acc)[BM / 32][BN / 64]) {
  constexpr int MI = BM / 32;          // wave tile M = BM/2
  constexpr int NI = BN / 64;          // wave tile N = BN/4
  constexpr int T = (BM + BN) / 128;   // 16B loads per lane per slot (512 lanes)
  constexpr int SLOT = (BM + BN) * 32; // u16 per slot
  const int tid = threadIdx.x;
  const int lane = tid & 63, wave = tid >> 6;
  const int wm = wave >> 2, wn = wave & 3, lr = lane & 15, quad = lane >> 4;

  const u16* gp[T];
#pragma unroll
  for (int t = 0; t < T; ++t) {
    const int c = t * 512 + wave * 64 + lane;
    if (c < BM * 4) {
      const int r = c >> 2;
      const int s = (c & 3) ^ ((r >> 1) & 3);
      gp[t] = A + (size_t)(m0 + r) * lda + s * 8;
    } else {
      const int cb = c - BM * 4;
      const int r = cb >> 2;
      const int s = (cb & 3) ^ ((r >> 1) & 3);
      gp[t] = Bt + (size_t)(n0 + r) * ldb + s * 8;
    }
  }
  const int wo = wave * 512;

  auto issue = [&](int slot, int kb) {
    u16* s = sh + slot * SLOT;
#pragma unroll
    for (int t = 0; t < T; ++t)
      g2l16(gp[t] + kb, s + t * 4096 + wo);   // 512 lanes x 16B = 4096 u16/round
  };

#pragma unroll
  for (int p = 0; p < DEPTH; ++p)
    issue(p, (p < kIters ? p : kIters - 1) * 32);

  const int xq = (quad ^ ((lr >> 1) & 3)) * 8;
  const int arow = wm * (BM / 2) + lr;
  const int brow = wn * (BN / 4) + lr;

  bf16x8 af[MI], b0[NI], b1[NI];
  S_WAITCNT_VM(T * (DEPTH - 1));
  __builtin_amdgcn_s_barrier();
#pragma unroll
  for (int ni = 0; ni < NI; ++ni)
    b0[ni] = *(const bf16x8*)(sh + BM * 32 + ((brow + ni * 16) * 32 + xq));
#pragma unroll
  for (int mi = 0; mi < MI; ++mi)
    af[mi] = *(const bf16x8*)(sh + ((arow + mi * 16) * 32 + xq));

  auto step = [&](int kt, bf16x8 (&bc)[NI], bf16x8 (&bn)[NI]) {
    S_WAITCNT_VM(T * (DEPTH - 2));
    __builtin_amdgcn_s_barrier();
    const int nx = (kt + 1 < kIters) ? kt + 1 : kIters - 1;
    u16* s1 = sh + (nx % DEPTH) * SLOT;
#pragma unroll
    for (int ni = 0; ni < NI; ++ni)
      bn[ni] = *(const bf16x8*)(s1 + BM * 32 + ((brow + ni * 16) * 32 + xq));
    __builtin_amdgcn_s_setprio(1);
#pragma unroll
    for (int mi = 0; mi < MI; ++mi) {
#pragma unroll
      for (int ni = 0; ni < NI; ++ni)
        acc[mi][ni] = __builtin_amdgcn_mfma_f32_16x16x32_bf16(af[mi], bc[ni], acc[mi][ni], 0, 0, 0);
      af[mi] = *(const bf16x8*)(s1 + ((arow + mi * 16) * 32 + xq));
    }
    __builtin_amdgcn_s_setprio(0);
    __builtin_amdgcn_s_barrier();
    const int kn = kt + DEPTH;
    issue(kn % DEPTH, (kn < kIters ? kn : kIters - 1) * 32);
  };

  for (int kt = 0; kt + 2 <= kIters; kt += 2) {
    step(kt, b0, b1);
    step(kt + 1, b1, b0);
  }
}

// ---------------------------------------------------------------------------
// R16 phase-split 8-wave pipe for scores (benched 50.8 us; frozen).
// BK=32, 3-slot LDS ring (96 KB), 2 sub-phases per K-step, counted vmcnt(4).
// ---------------------------------------------------------------------------
template <int BM, int BN>
__device__ __forceinline__ void gemm_bt_8w_4ph(
    const u16* __restrict__ A, const u16* __restrict__ Bt,
    int lda, int ldb, int kIters, int m0, int n0,
    u16* sh, f32x4 (&acc)[BM / 32][BN / 64]) {
  constexpr int T = (BM + BN) / 128;       // 4 g2l16 per thread per K-tile
  constexpr int SLOT = (BM + BN) * 32;     // u16 per K-tile slot (32 KB)
  const int tid = threadIdx.x;
  const int lane = tid & 63, wave = tid >> 6;
  const int wm = wave >> 2, wn = wave & 3, lr = lane & 15, quad = lane >> 4;

  const u16* gp[T];
#pragma unroll
  for (int t = 0; t < T; ++t) {
    const int c = t * 512 + wave * 64 + lane;
    if (c < BM * 4) {
      const int r = c >> 2;
      const int s = (c & 3) ^ ((r >> 1) & 3);
      gp[t] = A + (size_t)(m0 + r) * lda + s * 8;
    } else {
      const int cb = c - BM * 4;
      const int r = cb >> 2;
      const int s = (cb & 3) ^ ((r >> 1) & 3);
      gp[t] = Bt + (size_t)(n0 + r) * ldb + s * 8;
    }
  }
  const int wo = wave * 512;

#pragma unroll
  for (int p = 0; p < 2; ++p)
#pragma unroll
    for (int t = 0; t < T; ++t)
      g2l16(gp[t] + p * 32, sh + p * SLOT + t * 4096 + wo);
  S_WAITCNT_VM(4);
  __builtin_amdgcn_s_barrier();

  const int xq = (quad ^ ((lr >> 1) & 3)) * 8;
  const int abase = (wm * (BM / 2) + lr) * 32 + xq;            // + mi*512
  const int bbase = BM * 32 + (wn * (BN / 4) + lr) * 32 + xq;  // + ni*512

  int si = 0, s2 = 2;
  for (int kt = 0; kt < kIters; ++kt) {
    u16* slot = sh + si * SLOT;
    const int kn = kt + 2;
    const int kb = (kn < kIters ? kn : kIters - 1) * 32;
    u16* st = sh + s2 * SLOT + wo;

    bf16x8 a0[4], b0[4];
#pragma unroll
    for (int i = 0; i < 4; ++i)
      a0[i] = *(const bf16x8*)(slot + abase + i * 512);
#pragma unroll
    for (int j = 0; j < 4; ++j)
      b0[j] = *(const bf16x8*)(slot + bbase + j * 512);
    g2l16(gp[0] + kb, st);
    g2l16(gp[1] + kb, st + 4096);
    __builtin_amdgcn_s_barrier();
    S_WAITCNT_LGKM0;
    __builtin_amdgcn_s_setprio(1);
#pragma unroll
    for (int i = 0; i < 4; ++i)
#pragma unroll
      for (int j = 0; j < 4; ++j)
        acc[i][j] = __builtin_amdgcn_mfma_f32_16x16x32_bf16(a0[i], b0[j], acc[i][j], 0, 0, 0);
    __builtin_amdgcn_s_setprio(0);
    __builtin_amdgcn_s_barrier();
#pragma unroll
    for (int i = 0; i < 4; ++i)
      a0[i] = *(const bf16x8*)(slot + abase + (4 + i) * 512);
    g2l16(gp[2] + kb, st + 8192);
    g2l16(gp[3] + kb, st + 12288);
    __builtin_amdgcn_s_barrier();
    S_WAITCNT_LGKM0;
    __builtin_amdgcn_s_setprio(1);
#pragma unroll
    for (int i = 0; i < 4; ++i)
#pragma unroll
      for (int j = 0; j < 4; ++j)
        acc[4 + i][j] = __builtin_amdgcn_mfma_f32_16x16x32_bf16(a0[i], b0[j], acc[4 + i][j], 0, 0, 0);
    __builtin_amdgcn_s_setprio(0);
    S_WAITCNT_VM(4);
    __builtin_amdgcn_s_barrier();
    si = si == 2 ? 0 : si + 1;
    s2 = s2 == 2 ? 0 : s2 + 1;
  }
}

#define ZERO_ACC4(acc)                        \
  _Pragma("unroll") for (int mi = 0; mi < 4; ++mi) \
  _Pragma("unroll") for (int ni = 0; ni < 4; ++ni) \
      acc[mi][ni] = f32x4{0.f, 0.f, 0.f, 0.f};

// ---------------------------------------------------------------------------
// Full-line epilogue store (R7, proven). C-frag stored TRANSPOSED out[n][m]
// bf16. shfl_xor(16) pairs quads -> each lane stores 16 B of 8 consecutive m
// -> full 64 B lines. Optional exp(scale*x) + per-ni row-sum accumulation.
// ---------------------------------------------------------------------------
template <int MI>
__device__ __forceinline__ void epilogue_ct16(
    const f32x4 (&acc)[MI][4], u16* __restrict__ base, int m0w, int n0w,
    int ld, int lane, bool do_exp, float scale, float* rs) {
  const int lr = lane & 15, quad = lane >> 4;
  const int j = quad >> 1, par = quad & 1;
#pragma unroll
  for (int mp = 0; mp < MI / 2; ++mp) {
#pragma unroll
    for (int ni = 0; ni < 4; ++ni) {
      uint32_t p0[2], p1[2];
#pragma unroll
      for (int h = 0; h < 2; ++h) {
        const f32x4 v = acc[mp * 2 + h][ni];
        float e0, e1, e2, e3;
        if (do_exp) {
          e0 = __expf(v[0] * scale); e1 = __expf(v[1] * scale);
          e2 = __expf(v[2] * scale); e3 = __expf(v[3] * scale);
        } else {
          e0 = v[0]; e1 = v[1]; e2 = v[2]; e3 = v[3];
        }
        const u16 h0 = f2bf(e0), h1 = f2bf(e1), h2 = f2bf(e2), h3 = f2bf(e3);
        p0[h] = (uint32_t)h0 | ((uint32_t)h1 << 16);
        p1[h] = (uint32_t)h2 | ((uint32_t)h3 << 16);
        if (rs) rs[ni] += bf2f(h0) + bf2f(h1) + bf2f(h2) + bf2f(h3);
      }
      const uint32_t s0 = par ? p0[0] : p0[1];
      const uint32_t s1 = par ? p1[0] : p1[1];
      const uint32_t r0 = (uint32_t)__shfl_xor((int)s0, 16);
      const uint32_t r1 = (uint32_t)__shfl_xor((int)s1, 16);
      uint4 st;
      if (!par) { st.x = p0[0]; st.y = p1[0]; st.z = r0;    st.w = r1;    }
      else      { st.x = r0;    st.y = r1;    st.z = p0[1]; st.w = p1[1]; }
      const int m = m0w + 16 * (mp * 2 + par) + 8 * j;
      const int n = n0w + ni * 16 + lr;
      *(uint4*)(base + (size_t)n * ld + m) = st;
    }
  }
}

// ---------------------------------------------------------------------------
// k0: prep = convert_x (0..4095) + transpose_w (4096..4863) + L-zero (4864+)
// ---------------------------------------------------------------------------
__global__ __launch_bounds__(256) void prep_kernel(
    const float* __restrict__ x, u16* __restrict__ Xb,
    const float* __restrict__ W0, const float* __restrict__ W1,
    const float* __restrict__ W2, u16* __restrict__ Wt,
    float* __restrict__ L) {
  __shared__ float tile[32][33];
  const int id = blockIdx.x;
  if (id < 4096) {
    const int i = (id * 256 + threadIdx.x) * 4;
    const float4 v = *(const float4*)(x + i);
    u16x4_t h;
    h.x = f2bf(v.x); h.y = f2bf(v.y); h.z = f2bf(v.z); h.w = f2bf(v.w);
    *(u16x4_t*)(Xb + i) = h;
    return;
  }
  if (id >= 4864) {
    L[(id - 4864) * 256 + threadIdx.x] = 0.f;
    return;
  }
  const int t = id - 4096;
  const int wz = t >> 8, rem = t & 255;
  const float* W = wz == 0 ? W0 : (wz == 1 ? W1 : W2);
  u16* out = Wt + (size_t)wz * 512 * 512;
  const int bx = (rem & 15) * 32;
  const int by = (rem >> 4) * 32;
  const int tx = threadIdx.x & 31, ty = threadIdx.x >> 5;
#pragma unroll
  for (int i = 0; i < 32; i += 8)
    tile[ty + i][tx] = W[(size_t)(by + ty + i) * 512 + bx + tx];
  __syncthreads();
#pragma unroll
  for (int i = 0; i < 32; i += 8)
    out[(size_t)(bx + ty + i) * 512 + by + tx] = f2bf(tile[tx][ty + i]);
}

// ---------------------------------------------------------------------------
// k1 (R17): QKV projection, 8-wave 128(m)x256(n) tiles, 384 blocks.
// id<128: z=0 (Q), 128..255: z=1 (K): C[d][s] = Wt_z * Xb^T -> stores [s][d].
// id>=256: V: C[s][d] = Xb * Wt_v^T -> stores Vt[d][s].
// Halves epilogue/prologue count vs 768x128^2 (same staging bytes); DEPTH=3,
// 72 KB dynamic LDS -> 2 blocks/CU co-resident.
// ---------------------------------------------------------------------------
__global__ __launch_bounds__(512) void qkv_kernel(
    const u16* __restrict__ Xb, const u16* __restrict__ Wt,
    u16* __restrict__ Qb, u16* __restrict__ Kb, u16* __restrict__ Vt) {
  extern __shared__ u16 sh[];
  const int id = blockIdx.x;                 // 0..383
  int m0, n0;
  const u16 *A, *Bt;
  const bool isV = id >= 256;
  if (!isV) {
    const int q = id & 127;
    m0 = (q >> 5) * 128;                     // 4 d-tiles
    n0 = (q & 31) * 256;                     // 32 s-tiles
    A = Wt + (size_t)(id >> 7) * 512 * 512;
    Bt = Xb;
  } else {
    const int v = id - 256;                  // 0..127
    m0 = (v >> 1) * 128;                     // 64 s-tiles
    n0 = (v & 1) * 256;                      // 2 d-tiles
    A = Xb;
    Bt = Wt + (size_t)2 * 512 * 512;
  }
  f32x4 acc[4][4];
  ZERO_ACC4(acc);
  gemm_bt_pipe_w8<3, 128, 256>(A, Bt, 512, 512, 16, m0, n0, sh, acc);

  const int lane = threadIdx.x & 63, wave = threadIdx.x >> 6;
  const int wm = wave >> 2, wn = wave & 3;
  if (!isV) {
    epilogue_ct16<4>(acc, (id >> 7) == 0 ? Qb : Kb, m0 + wm * 64, n0 + wn * 64,
                     512, lane, false, 1.f, nullptr);
  } else {
    const int bb = m0 >> 12;
    epilogue_ct16<4>(acc, Vt + (size_t)bb * 512 * 4096,
                     (m0 & 4095) + wm * 64, n0 + wn * 64, 4096,
                     lane, false, 1.f, nullptr);
  }
}

// ---------------------------------------------------------------------------
// k2 (R16, frozen): S^T tile (A=K, B=Q), 256x256 per block, 8 waves, phase-
// split pipe, 96 KB dynamic LDS. Epilogue fuses exp(S/sqrt(512)), bf16 pack,
// row-sum, full-line row-major P stores; L[q] += row sums.
// ---------------------------------------------------------------------------
__global__ __launch_bounds__(512, 2) void scores_kernel(
    const u16* __restrict__ Qb, const u16* __restrict__ Kb,
    u16* __restrict__ P, float* __restrict__ L) {
  extern __shared__ u16 sh[];
  const int id = blockIdx.x;                 // 0..511
  const int b = id >> 8;
  const int r = id & 255;
  const int j = r >> 3;
  const int qx = (r & 7) * 2 + (j >> 4);     // Q tile 0..15 (2 per XCD)
  const int ky = j & 15;                     // KEY tile 0..15
  const int m0 = ky * 256;                   // KEY tile base
  const int n0 = qx * 256;                   // Q tile base
  f32x4 acc[8][4];
#pragma unroll
  for (int mi = 0; mi < 8; ++mi)
#pragma unroll
    for (int ni = 0; ni < 4; ++ni)
      acc[mi][ni] = f32x4{0.f, 0.f, 0.f, 0.f};
  // A = K (m = key), Bt = Q (n = q)  =>  C[key][q] = S[q][key]
  gemm_bt_8w_4ph<256, 256>(Kb + (size_t)b * 4096 * 512,
                           Qb + (size_t)b * 4096 * 512,
                           512, 512, 16, m0, n0, sh, acc);

  const int lane = threadIdx.x & 63, wave = threadIdx.x >> 6;
  const int wm = wave >> 2, wn = wave & 3, lr = lane & 15, quad = lane >> 4;
  const float scale = 0.04419417382415922f;  // 1/sqrt(512)
  u16* Pb = P + (size_t)b * 4096 * 4096;

  float rs[4] = {0.f, 0.f, 0.f, 0.f};
  epilogue_ct16<8>(acc, Pb, m0 + wm * 128, n0 + wn * 64, 4096, lane, true,
                   scale, rs);

#pragma unroll
  for (int ni = 0; ni < 4; ++ni) {
    float v = rs[ni];
    v += __shfl_xor(v, 16);
    v += __shfl_xor(v, 32);
    if (quad == 0)
      atomicAdd(&L[b * 4096 + n0 + wn * 64 + ni * 16 + lr], v);
  }
}

// ---------------------------------------------------------------------------
// k3 (R17): pv single-K: 128x128 tile, K=4096 (128 steps -- the pipeline's
// best GEMM shape), 256 blocks = exactly 1 co-resident round, DEPTH=3 (48 KB).
// Fused normalize epilogue: out = acc / L[row] (L complete: stream-ordered
// after scores). Kills split-K, part0 round-trip (33 MB) and reduce kernel
// (48 MB, ~8 us). Grid decode: xcd = id%8 -> b = xcd&1 fixed per XCD; the 4
// d-tiles (ntile) of one (b,mtile) land on the SAME XCD and stream the same
// 1 MB P-stripe through its L2 -> P fetched once total; Vt (16 MB) via L3.
// ---------------------------------------------------------------------------
__global__ __launch_bounds__(256) void pv_kernel(
    const u16* __restrict__ P, const u16* __restrict__ Vt,
    const float* __restrict__ L, float* __restrict__ out) {
  __shared__ u16 sh[3 * 8192];               // DEPTH=3 x 16 KB = 48 KB
  const int id = blockIdx.x;                 // 0..255
  const int xcd = id & 7, s = id >> 3;       // s: 0..31
  const int g = s >> 2, ntile = s & 3;       // g: 0..7
  const int G = xcd + 8 * g;                 // 0..63
  const int b = G & 1;                       // = xcd & 1 (fixed per XCD)
  const int mtile = G >> 1;                  // 0..31
  const int m0 = mtile * 128;                // q-tile base
  const int n0 = ntile * 128;                // d-tile base
  f32x4 acc[4][4];
  ZERO_ACC4(acc);
  gemm_bt_pipe<3, 128, 128>(P + (size_t)b * 4096 * 4096,
                            Vt + (size_t)b * 512 * 4096,
                            4096, 4096, 128, m0, n0, sh, acc);

  const int lane = threadIdx.x & 63, wave = threadIdx.x >> 6;
  const int wm = wave >> 1, wn = wave & 1, lr = lane & 15, quad = lane >> 4;
  const float* Lb = L + b * 4096;
#pragma unroll
  for (int mi = 0; mi < 4; ++mi) {
    const int row = m0 + wm * 64 + mi * 16 + quad * 4;
#pragma unroll
    for (int i = 0; i < 4; ++i) {
      const float rinv = 1.0f / Lb[row + i];
#pragma unroll
      for (int ni = 0; ni < 4; ++ni) {
        const int col = n0 + wn * 64 + ni * 16 + lr;  // 16 consec fp32 = 64 B
        out[(size_t)b * 2097152 + (size_t)(row + i) * 512 + col] =
            acc[mi][ni][i] * rinv;
      }
    }
  }
}

// ---------------------------------------------------------------------------
// Workspace layout (bytes):
//   Xb    @ 0         : 8,388,608
//   Qb    @ 8388608   : 8,388,608
//   Kb    @ 16777216  : 8,388,608
//   Vt    @ 25165824  : 8,388,608
//   Wt    @ 33554432  : 1,572,864
//   P     @ 35127296  : 67,108,864  (row-major [b][q][key], bf16)
//   L     @ 102236160 : 32,768
// ---------------------------------------------------------------------------
extern "C" void kernel_launch(void* const* d_in, const int* in_sizes, int n_in,
                              void* d_out, int out_size, void* d_ws, size_t ws_size,
                              hipStream_t stream) {
  const float* x  = (const float*)d_in[0];
  const float* Wq = (const float*)d_in[1];
  const float* Wk = (const float*)d_in[2];
  const float* Wv = (const float*)d_in[3];
  float* out = (float*)d_out;
  char* ws = (char*)d_ws;
  u16* Xb = (u16*)(ws);
  u16* Qb = (u16*)(ws + 8388608);
  u16* Kb = (u16*)(ws + 16777216);
  u16* Vt = (u16*)(ws + 25165824);
  u16* Wt = (u16*)(ws + 33554432);
  u16* P  = (u16*)(ws + 35127296);
  float* L = (float*)(ws + 102236160);

  static bool attr_set = false;
  if (!attr_set) {
    hipFuncSetAttribute(reinterpret_cast<const void*>(scores_kernel),
                        hipFuncAttributeMaxDynamicSharedMemorySize, 98304);
    hipFuncSetAttribute(reinterpret_cast<const void*>(qkv_kernel),
                        hipFuncAttributeMaxDynamicSharedMemorySize, 73728);
    attr_set = true;
  }

  prep_kernel<<<4896, 256, 0, stream>>>(x, Xb, Wq, Wk, Wv, Wt, L);
  qkv_kernel<<<384, 512, 73728, stream>>>(Xb, Wt, Qb, Kb, Vt);
  scores_kernel<<<512, 512, 98304, stream>>>(Qb, Kb, P, L);
  pv_kernel<<<256, 256, 0, stream>>>(P, Vt, L, out);
}

// Round 7
// 181.243 us; speedup vs baseline: 1.0902x; 1.0902x over previous
//
#include <hip/hip_runtime.h>
#include <cstdint>
#include <cstddef>

typedef unsigned short u16;
typedef __attribute__((ext_vector_type(8))) short bf16x8;
typedef __attribute__((ext_vector_type(4))) float f32x4;

struct alignas(8) u16x4_t { u16 x, y, z, w; };

__device__ __forceinline__ u16 f2bf(float f) {
  uint32_t u = __builtin_bit_cast(uint32_t, f);
  u += 0x7FFFu + ((u >> 16) & 1u);          // round-to-nearest-even
  return (u16)(u >> 16);
}
__device__ __forceinline__ float bf2f(u16 h) {
  uint32_t u = ((uint32_t)h) << 16;
  return __builtin_bit_cast(float, u);
}

// async global->LDS, 16B per lane. LDS dest is wave-uniform base; HW adds lane*16.
// NOTE (R10 post-mortem): this is the ONLY sound async-staging primitive from
// HIP source. Direct global->VGPR via inline asm is unsound. Do not retry.
__device__ __forceinline__ void g2l16(const u16* g, u16* l) {
  __builtin_amdgcn_global_load_lds(
      (const __attribute__((address_space(1))) void*)g,
      (__attribute__((address_space(3))) void*)l, 16, 0, 0);
}

// gfx9 s_waitcnt imm: vmcnt[3:0]@0, expcnt@4 (3b), lgkmcnt@8 (4b), vmcnt[5:4]@14
#define S_WAITCNT_VM(N) \
  __builtin_amdgcn_s_waitcnt((((N) & 0xF)) | (0x7 << 4) | (0xF << 8) | ((((N) >> 4) & 3) << 14))
#define S_WAITCNT_LGKM0 __builtin_amdgcn_s_waitcnt(0xC07F)

// ---------------------------------------------------------------------------
// R15 software-pipelined bt-GEMM ring (4 waves of 256 consecutive threads).
// R18: takes explicit `tid` so TWO groups of 4 waves in one 512-thread block
// can each run an independent pipe (own LDS region, own k-range). Barriers
// inside are BLOCK-wide s_barrier: cadence across groups must be identical
// (same kIters, same code path) -- holds for pv's wave-split-K.
// SESSION LAW (R14/R17): every well-performing config had >=8 waves/CU;
// dropping below (1 blk/CU x 4 waves, or VGPR-capped spill) always lost.
// ---------------------------------------------------------------------------
template <int DEPTH, int BM, int BN>
__device__ __forceinline__ void gemm_bt_pipe(
    const u16* __restrict__ A, const u16* __restrict__ Bt,
    int lda, int ldb, int kIters, int m0, int n0,
    u16* sh, f32x4 (&acc)[BM / 32][BN / 32], int tid) {
  constexpr int MI = BM / 32;
  constexpr int NI = BN / 32;
  constexpr int T = (BM + BN) / 64;
  constexpr int SLOT = (BM + BN) * 32;
  const int lane = tid & 63, wave = tid >> 6;
  const int wm = wave >> 1, wn = wave & 1, lr = lane & 15, quad = lane >> 4;

  const u16* gp[T];
#pragma unroll
  for (int t = 0; t < T; ++t) {
    const int c = t * 256 + wave * 64 + lane;
    if (c < BM * 4) {
      const int r = c >> 2;
      const int s = (c & 3) ^ ((r >> 1) & 3);
      gp[t] = A + (size_t)(m0 + r) * lda + s * 8;
    } else {
      const int cb = c - BM * 4;
      const int r = cb >> 2;
      const int s = (cb & 3) ^ ((r >> 1) & 3);
      gp[t] = Bt + (size_t)(n0 + r) * ldb + s * 8;
    }
  }
  const int wo = wave * 512;

  auto issue = [&](int slot, int kb) {
    u16* s = sh + slot * SLOT;
#pragma unroll
    for (int t = 0; t < T; ++t)
      g2l16(gp[t] + kb, s + t * 2048 + wo);
  };

#pragma unroll
  for (int p = 0; p < DEPTH; ++p)
    issue(p, (p < kIters ? p : kIters - 1) * 32);

  const int xq = (quad ^ ((lr >> 1) & 3)) * 8;
  const int arow = wm * (BM / 2) + lr;     // + mi*16
  const int brow = wn * (BN / 2) + lr;     // + ni*16

  bf16x8 af[MI], b0[NI], b1[NI];
  S_WAITCNT_VM(T * (DEPTH - 1));           // tile 0 landed (own)
  __builtin_amdgcn_s_barrier();            // tile 0 landed (all waves)
#pragma unroll
  for (int ni = 0; ni < NI; ++ni)
    b0[ni] = *(const bf16x8*)(sh + BM * 32 + ((brow + ni * 16) * 32 + xq));
#pragma unroll
  for (int mi = 0; mi < MI; ++mi)
    af[mi] = *(const bf16x8*)(sh + ((arow + mi * 16) * 32 + xq));

  auto step = [&](int kt, bf16x8 (&bc)[NI], bf16x8 (&bn)[NI]) {
    S_WAITCNT_VM(T * (DEPTH - 2));         // tiles <= kt+1 landed (own)
    __builtin_amdgcn_s_barrier();          // ... landed (all waves)
    const int nx = (kt + 1 < kIters) ? kt + 1 : kIters - 1;  // clamped tail
    u16* s1 = sh + (nx % DEPTH) * SLOT;
#pragma unroll
    for (int ni = 0; ni < NI; ++ni)
      bn[ni] = *(const bf16x8*)(s1 + BM * 32 + ((brow + ni * 16) * 32 + xq));
    __builtin_amdgcn_s_setprio(1);
#pragma unroll
    for (int mi = 0; mi < MI; ++mi) {
#pragma unroll
      for (int ni = 0; ni < NI; ++ni)
        acc[mi][ni] = __builtin_amdgcn_mfma_f32_16x16x32_bf16(af[mi], bc[ni], acc[mi][ni], 0, 0, 0);
      af[mi] = *(const bf16x8*)(s1 + ((arow + mi * 16) * 32 + xq));  // next tile
    }
    __builtin_amdgcn_s_setprio(0);
    __builtin_amdgcn_s_barrier();          // all tile-kt reads drained (by MFMAs)
    const int kn = kt + DEPTH;
    issue(kn % DEPTH, (kn < kIters ? kn : kIters - 1) * 32);
  };

  for (int kt = 0; kt + 2 <= kIters; kt += 2) {  // kIters even everywhere
    step(kt, b0, b1);
    step(kt + 1, b1, b0);
  }
}

// ---------------------------------------------------------------------------
// R16 phase-split 8-wave pipe for scores (benched 50.8 us; frozen).
// BK=32, 3-slot LDS ring (96 KB), 2 sub-phases per K-step, counted vmcnt(4).
// ---------------------------------------------------------------------------
template <int BM, int BN>
__device__ __forceinline__ void gemm_bt_8w_4ph(
    const u16* __restrict__ A, const u16* __restrict__ Bt,
    int lda, int ldb, int kIters, int m0, int n0,
    u16* sh, f32x4 (&acc)[BM / 32][BN / 64]) {
  constexpr int T = (BM + BN) / 128;       // 4 g2l16 per thread per K-tile
  constexpr int SLOT = (BM + BN) * 32;     // u16 per K-tile slot (32 KB)
  const int tid = threadIdx.x;
  const int lane = tid & 63, wave = tid >> 6;
  const int wm = wave >> 2, wn = wave & 3, lr = lane & 15, quad = lane >> 4;

  const u16* gp[T];
#pragma unroll
  for (int t = 0; t < T; ++t) {
    const int c = t * 512 + wave * 64 + lane;
    if (c < BM * 4) {
      const int r = c >> 2;
      const int s = (c & 3) ^ ((r >> 1) & 3);
      gp[t] = A + (size_t)(m0 + r) * lda + s * 8;
    } else {
      const int cb = c - BM * 4;
      const int r = cb >> 2;
      const int s = (cb & 3) ^ ((r >> 1) & 3);
      gp[t] = Bt + (size_t)(n0 + r) * ldb + s * 8;
    }
  }
  const int wo = wave * 512;

#pragma unroll
  for (int p = 0; p < 2; ++p)
#pragma unroll
    for (int t = 0; t < T; ++t)
      g2l16(gp[t] + p * 32, sh + p * SLOT + t * 4096 + wo);
  S_WAITCNT_VM(4);
  __builtin_amdgcn_s_barrier();

  const int xq = (quad ^ ((lr >> 1) & 3)) * 8;
  const int abase = (wm * (BM / 2) + lr) * 32 + xq;            // + mi*512
  const int bbase = BM * 32 + (wn * (BN / 4) + lr) * 32 + xq;  // + ni*512

  int si = 0, s2 = 2;
  for (int kt = 0; kt < kIters; ++kt) {
    u16* slot = sh + si * SLOT;
    const int kn = kt + 2;
    const int kb = (kn < kIters ? kn : kIters - 1) * 32;
    u16* st = sh + s2 * SLOT + wo;

    bf16x8 a0[4], b0[4];
#pragma unroll
    for (int i = 0; i < 4; ++i)
      a0[i] = *(const bf16x8*)(slot + abase + i * 512);
#pragma unroll
    for (int j = 0; j < 4; ++j)
      b0[j] = *(const bf16x8*)(slot + bbase + j * 512);
    g2l16(gp[0] + kb, st);
    g2l16(gp[1] + kb, st + 4096);
    __builtin_amdgcn_s_barrier();
    S_WAITCNT_LGKM0;
    __builtin_amdgcn_s_setprio(1);
#pragma unroll
    for (int i = 0; i < 4; ++i)
#pragma unroll
      for (int j = 0; j < 4; ++j)
        acc[i][j] = __builtin_amdgcn_mfma_f32_16x16x32_bf16(a0[i], b0[j], acc[i][j], 0, 0, 0);
    __builtin_amdgcn_s_setprio(0);
    __builtin_amdgcn_s_barrier();
#pragma unroll
    for (int i = 0; i < 4; ++i)
      a0[i] = *(const bf16x8*)(slot + abase + (4 + i) * 512);
    g2l16(gp[2] + kb, st + 8192);
    g2l16(gp[3] + kb, st + 12288);
    __builtin_amdgcn_s_barrier();
    S_WAITCNT_LGKM0;
    __builtin_amdgcn_s_setprio(1);
#pragma unroll
    for (int i = 0; i < 4; ++i)
#pragma unroll
      for (int j = 0; j < 4; ++j)
        acc[4 + i][j] = __builtin_amdgcn_mfma_f32_16x16x32_bf16(a0[i], b0[j], acc[4 + i][j], 0, 0, 0);
    __builtin_amdgcn_s_setprio(0);
    S_WAITCNT_VM(4);
    __builtin_amdgcn_s_barrier();
    si = si == 2 ? 0 : si + 1;
    s2 = s2 == 2 ? 0 : s2 + 1;
  }
}

#define ZERO_ACC4(acc)                        \
  _Pragma("unroll") for (int mi = 0; mi < 4; ++mi) \
  _Pragma("unroll") for (int ni = 0; ni < 4; ++ni) \
      acc[mi][ni] = f32x4{0.f, 0.f, 0.f, 0.f};

// ---------------------------------------------------------------------------
// Full-line epilogue store (R7, proven). C-frag stored TRANSPOSED out[n][m]
// bf16. shfl_xor(16) pairs quads -> each lane stores 16 B of 8 consecutive m
// -> full 64 B lines. Optional exp(scale*x) + per-ni row-sum accumulation.
// ---------------------------------------------------------------------------
template <int MI>
__device__ __forceinline__ void epilogue_ct16(
    const f32x4 (&acc)[MI][4], u16* __restrict__ base, int m0w, int n0w,
    int ld, int lane, bool do_exp, float scale, float* rs) {
  const int lr = lane & 15, quad = lane >> 4;
  const int j = quad >> 1, par = quad & 1;
#pragma unroll
  for (int mp = 0; mp < MI / 2; ++mp) {
#pragma unroll
    for (int ni = 0; ni < 4; ++ni) {
      uint32_t p0[2], p1[2];
#pragma unroll
      for (int h = 0; h < 2; ++h) {
        const f32x4 v = acc[mp * 2 + h][ni];
        float e0, e1, e2, e3;
        if (do_exp) {
          e0 = __expf(v[0] * scale); e1 = __expf(v[1] * scale);
          e2 = __expf(v[2] * scale); e3 = __expf(v[3] * scale);
        } else {
          e0 = v[0]; e1 = v[1]; e2 = v[2]; e3 = v[3];
        }
        const u16 h0 = f2bf(e0), h1 = f2bf(e1), h2 = f2bf(e2), h3 = f2bf(e3);
        p0[h] = (uint32_t)h0 | ((uint32_t)h1 << 16);
        p1[h] = (uint32_t)h2 | ((uint32_t)h3 << 16);
        if (rs) rs[ni] += bf2f(h0) + bf2f(h1) + bf2f(h2) + bf2f(h3);
      }
      const uint32_t s0 = par ? p0[0] : p0[1];
      const uint32_t s1 = par ? p1[0] : p1[1];
      const uint32_t r0 = (uint32_t)__shfl_xor((int)s0, 16);
      const uint32_t r1 = (uint32_t)__shfl_xor((int)s1, 16);
      uint4 st;
      if (!par) { st.x = p0[0]; st.y = p1[0]; st.z = r0;    st.w = r1;    }
      else      { st.x = r0;    st.y = r1;    st.z = p0[1]; st.w = p1[1]; }
      const int m = m0w + 16 * (mp * 2 + par) + 8 * j;
      const int n = n0w + ni * 16 + lr;
      *(uint4*)(base + (size_t)n * ld + m) = st;
    }
  }
}

// ---------------------------------------------------------------------------
// k0: prep = convert_x (0..4095) + transpose_w (4096..4863) + L-zero (4864+)
// ---------------------------------------------------------------------------
__global__ __launch_bounds__(256) void prep_kernel(
    const float* __restrict__ x, u16* __restrict__ Xb,
    const float* __restrict__ W0, const float* __restrict__ W1,
    const float* __restrict__ W2, u16* __restrict__ Wt,
    float* __restrict__ L) {
  __shared__ float tile[32][33];
  const int id = blockIdx.x;
  if (id < 4096) {
    const int i = (id * 256 + threadIdx.x) * 4;
    const float4 v = *(const float4*)(x + i);
    u16x4_t h;
    h.x = f2bf(v.x); h.y = f2bf(v.y); h.z = f2bf(v.z); h.w = f2bf(v.w);
    *(u16x4_t*)(Xb + i) = h;
    return;
  }
  if (id >= 4864) {
    L[(id - 4864) * 256 + threadIdx.x] = 0.f;
    return;
  }
  const int t = id - 4096;
  const int wz = t >> 8, rem = t & 255;
  const float* W = wz == 0 ? W0 : (wz == 1 ? W1 : W2);
  u16* out = Wt + (size_t)wz * 512 * 512;
  const int bx = (rem & 15) * 32;
  const int by = (rem >> 4) * 32;
  const int tx = threadIdx.x & 31, ty = threadIdx.x >> 5;
#pragma unroll
  for (int i = 0; i < 32; i += 8)
    tile[ty + i][tx] = W[(size_t)(by + ty + i) * 512 + bx + tx];
  __syncthreads();
#pragma unroll
  for (int i = 0; i < 32; i += 8)
    out[(size_t)(bx + ty + i) * 512 + by + tx] = f2bf(tile[tx][ty + i]);
}

// ---------------------------------------------------------------------------
// k1: QKV projection -- REVERTED to the measured-good R9/R13 config (4-wave,
// 128x128, 768 blocks, static 48 KB): R17's 8-wave/384-block variant cost
// ~+10 us (1.5 blocks/CU -> half-idle second round).
// z<2 (Q,K): C[d][s] = Wt_z * Xb^T -> epilogue stores Q/K[s][d] full-line.
// z=2 (V):   C[s][d] = Xb * Wt_v^T -> epilogue stores Vt[d][s] (bt for pv).
// ---------------------------------------------------------------------------
__global__ __launch_bounds__(256) void qkv_kernel(
    const u16* __restrict__ Xb, const u16* __restrict__ Wt,
    u16* __restrict__ Qb, u16* __restrict__ Kb, u16* __restrict__ Vt) {
  __shared__ u16 sh[3 * 8192];
  const int z = blockIdx.z;
  int m0, n0;
  const u16 *A, *Bt;
  if (z < 2) {
    m0 = blockIdx.y * 128;
    n0 = blockIdx.x * 128;
    A = Wt + (size_t)z * 512 * 512;
    Bt = Xb;
  } else {
    m0 = blockIdx.x * 128;
    n0 = blockIdx.y * 128;
    A = Xb;
    Bt = Wt + (size_t)2 * 512 * 512;
  }
  f32x4 acc[4][4];
  ZERO_ACC4(acc);
  gemm_bt_pipe<3, 128, 128>(A, Bt, 512, 512, 16, m0, n0, sh, acc, threadIdx.x);

  const int lane = threadIdx.x & 63, wave = threadIdx.x >> 6;
  const int wm = wave >> 1, wn = wave & 1;
  if (z < 2) {
    epilogue_ct16<4>(acc, z == 0 ? Qb : Kb, m0 + wm * 64, n0 + wn * 64, 512,
                     lane, false, 1.f, nullptr);
  } else {
    const int bb = m0 >> 12;
    epilogue_ct16<4>(acc, Vt + (size_t)bb * 512 * 4096,
                     (m0 & 4095) + wm * 64, n0 + wn * 64, 4096,
                     lane, false, 1.f, nullptr);
  }
}

// ---------------------------------------------------------------------------
// k2 (R16, frozen): S^T tile (A=K, B=Q), 256x256 per block, 8 waves, phase-
// split pipe, 96 KB dynamic LDS. Epilogue fuses exp(S/sqrt(512)), bf16 pack,
// row-sum, full-line row-major P stores; L[q] += row sums.
// ---------------------------------------------------------------------------
__global__ __launch_bounds__(512, 2) void scores_kernel(
    const u16* __restrict__ Qb, const u16* __restrict__ Kb,
    u16* __restrict__ P, float* __restrict__ L) {
  extern __shared__ u16 sh[];
  const int id = blockIdx.x;                 // 0..511
  const int b = id >> 8;
  const int r = id & 255;
  const int j = r >> 3;
  const int qx = (r & 7) * 2 + (j >> 4);     // Q tile 0..15 (2 per XCD)
  const int ky = j & 15;                     // KEY tile 0..15
  const int m0 = ky * 256;                   // KEY tile base
  const int n0 = qx * 256;                   // Q tile base
  f32x4 acc[8][4];
#pragma unroll
  for (int mi = 0; mi < 8; ++mi)
#pragma unroll
    for (int ni = 0; ni < 4; ++ni)
      acc[mi][ni] = f32x4{0.f, 0.f, 0.f, 0.f};
  // A = K (m = key), Bt = Q (n = q)  =>  C[key][q] = S[q][key]
  gemm_bt_8w_4ph<256, 256>(Kb + (size_t)b * 4096 * 512,
                           Qb + (size_t)b * 4096 * 512,
                           512, 512, 16, m0, n0, sh, acc);

  const int lane = threadIdx.x & 63, wave = threadIdx.x >> 6;
  const int wm = wave >> 2, wn = wave & 3, lr = lane & 15, quad = lane >> 4;
  const float scale = 0.04419417382415922f;  // 1/sqrt(512)
  u16* Pb = P + (size_t)b * 4096 * 4096;

  float rs[4] = {0.f, 0.f, 0.f, 0.f};
  epilogue_ct16<8>(acc, Pb, m0 + wm * 128, n0 + wn * 64, 4096, lane, true,
                   scale, rs);

#pragma unroll
  for (int ni = 0; ni < 4; ++ni) {
    float v = rs[ni];
    v += __shfl_xor(v, 16);
    v += __shfl_xor(v, 32);
    if (quad == 0)
      atomicAdd(&L[b * 4096 + n0 + wn * 64 + ni * 16 + lr], v);
  }
}

// ---------------------------------------------------------------------------
// k3 (R18): pv with WAVE-SPLIT-K. 256 blocks x 512 threads: 8 waves = 2
// K-groups x 4 waves. Each group runs the unmodified 4-wave ring on its own
// half-K (own 48 KB LDS region, own k0). Barrier cadence identical across
// groups (same kIters=64, same path) -> block-wide s_barrier sound; vmcnt is
// per-wave -> counts unchanged. Residency 8 waves/CU = 2/SIMD (the proven
// split-K x2 timeline) WITHOUT part0 HBM round-trip (33 MB) or the reduce
// kernel (48 MB + launch). Cross-K combine in LDS (stride-65 f32 -> 2-way
// bank aliasing = free); normalize 1/L fused into the store (L complete:
// stream-ordered after scores).
// ---------------------------------------------------------------------------
__global__ __launch_bounds__(512) void pv_kernel(
    const u16* __restrict__ P, const u16* __restrict__ Vt,
    const float* __restrict__ L, float* __restrict__ out) {
  extern __shared__ u16 sh[];                // 96 KB: 2 x (DEPTH=3 x 16 KB)
  const int id = blockIdx.x;                 // 0..255
  const int xcd = id & 7, s = id >> 3;       // s: 0..31
  const int g = s >> 2, ntile = s & 3;       // g: 0..7
  const int G = xcd + 8 * g;                 // 0..63
  const int b = G & 1;                       // fixed per XCD
  const int mtile = G >> 1;                  // 0..31
  const int m0 = mtile * 128;                // q-tile base
  const int n0 = ntile * 128;                // d-tile base

  const int wave8 = threadIdx.x >> 6;        // 0..7
  const int kg = wave8 >> 2;                 // K-group 0/1
  const int tid4 = threadIdx.x & 255;        // tid within group
  const int k0 = kg * 2048;                  // group's half-K base (bf16 elems)

  f32x4 acc[4][4];
  ZERO_ACC4(acc);
  gemm_bt_pipe<3, 128, 128>(P + (size_t)b * 4096 * 4096 + k0,
                            Vt + (size_t)b * 512 * 4096 + k0,
                            4096, 4096, 64, m0, n0,
                            sh + kg * 24576, acc, tid4);

  // Drain in-flight tail stages before reusing LDS for the combine.
  S_WAITCNT_VM(0);
  __builtin_amdgcn_s_barrier();

  const int iw = wave8 & 3;                  // wave-in-group
  const int lane = threadIdx.x & 63;
  float* cs = (float*)sh;
  float* reg = cs + iw * 4160 + lane * 65;   // stride 65: (65l+j)%32=(l+j)%32

  if (kg == 1) {
#pragma unroll
    for (int mi = 0; mi < 4; ++mi)
#pragma unroll
      for (int ni = 0; ni < 4; ++ni)
#pragma unroll
        for (int i = 0; i < 4; ++i)
          reg[mi * 16 + ni * 4 + i] = acc[mi][ni][i];
  }
  __syncthreads();
  if (kg == 0) {
    const int wm = iw >> 1, wn = iw & 1, lr = lane & 15, quad = lane >> 4;
    const float* Lb = L + b * 4096;
#pragma unroll
    for (int mi = 0; mi < 4; ++mi) {
      const int row = m0 + wm * 64 + mi * 16 + quad * 4;
#pragma unroll
      for (int i = 0; i < 4; ++i) {
        const float rinv = 1.0f / Lb[row + i];
#pragma unroll
        for (int ni = 0; ni < 4; ++ni) {
          const int col = n0 + wn * 64 + ni * 16 + lr;  // 16 consec fp32 = 64 B
          out[(size_t)b * 2097152 + (size_t)(row + i) * 512 + col] =
              (acc[mi][ni][i] + reg[mi * 16 + ni * 4 + i]) * rinv;
        }
      }
    }
  }
}

// ---------------------------------------------------------------------------
// Workspace layout (bytes):
//   Xb    @ 0         : 8,388,608
//   Qb    @ 8388608   : 8,388,608
//   Kb    @ 16777216  : 8,388,608
//   Vt    @ 25165824  : 8,388,608
//   Wt    @ 33554432  : 1,572,864
//   P     @ 35127296  : 67,108,864  (row-major [b][q][key], bf16)
//   L     @ 102236160 : 32,768
// ---------------------------------------------------------------------------
extern "C" void kernel_launch(void* const* d_in, const int* in_sizes, int n_in,
                              void* d_out, int out_size, void* d_ws, size_t ws_size,
                              hipStream_t stream) {
  const float* x  = (const float*)d_in[0];
  const float* Wq = (const float*)d_in[1];
  const float* Wk = (const float*)d_in[2];
  const float* Wv = (const float*)d_in[3];
  float* out = (float*)d_out;
  char* ws = (char*)d_ws;
  u16* Xb = (u16*)(ws);
  u16* Qb = (u16*)(ws + 8388608);
  u16* Kb = (u16*)(ws + 16777216);
  u16* Vt = (u16*)(ws + 25165824);
  u16* Wt = (u16*)(ws + 33554432);
  u16* P  = (u16*)(ws + 35127296);
  float* L = (float*)(ws + 102236160);

  static bool attr_set = false;
  if (!attr_set) {
    hipFuncSetAttribute(reinterpret_cast<const void*>(scores_kernel),
                        hipFuncAttributeMaxDynamicSharedMemorySize, 98304);
    hipFuncSetAttribute(reinterpret_cast<const void*>(pv_kernel),
                        hipFuncAttributeMaxDynamicSharedMemorySize, 98304);
    attr_set = true;
  }

  prep_kernel<<<4896, 256, 0, stream>>>(x, Xb, Wq, Wk, Wv, Wt, L);
  qkv_kernel<<<dim3(64, 4, 3), 256, 0, stream>>>(Xb, Wt, Qb, Kb, Vt);
  scores_kernel<<<512, 512, 98304, stream>>>(Qb, Kb, P, L);
  pv_kernel<<<256, 512, 98304, stream>>>(P, Vt, L, out);
}